// Round 1
// baseline (706.816 us; speedup 1.0000x reference)
//
#include <hip/hip_runtime.h>

// Problem constants (fixed shapes from setup_inputs)
#define BATCH   8
#define DIM     8
#define NPIX    (1024 * 1024)
#define NCLS    5
#define SIGMA_V 0.5f
#define SIGMA_D 3.0f

#define PBLK 256                 // blocks per sample (2048 total = 8 blocks/CU)
#define TPB  256                 // threads per block = 4 waves
#define NWAVE (TPB / 64)
#define NBLOCKS (PBLK * BATCH)   // 2048
#define NIT ((NPIX / 4) / (PBLK * 64))   // 16 iterations, exact coverage

// ws layout: float ws[BATCH][NCLS][10] -> per (b,c): [count, sumsq, sum[0..7]]
// then one uint ticket at ws[WS_FLOATS]
#define ACC50 (NCLS * 10)
#define WS_FLOATS (BATCH * ACC50)   // 400
#define WS_TOTAL  (WS_FLOATS + 4)   // + ticket (+ pad)

typedef float v2f __attribute__((ext_vector_type(2)));

__global__ void lanenet_init_ws(float* __restrict__ ws) {
    int t = blockIdx.x * blockDim.x + threadIdx.x;
    if (t < WS_TOTAL) ws[t] = 0.0f;   // also zeroes the ticket counter
}

__device__ __forceinline__ float wave_sum(float v) {
    #pragma unroll
    for (int off = 32; off > 0; off >>= 1)
        v += __shfl_xor(v, off, 64);
    return v;
}

// Dim-split accumulation: wave w handles dims {2w, 2w+1} over the SAME pixel
// range. Packed accumulators: cs[c]=(cnt,sq) sm[c]=(sm0,sm1) -> v_pk_fma_f32
// halves the fma instruction count vs scalar (bit-identical math).
// Explicit 1-deep rotation keeps next iteration's 3 loads (3KB/wave) in
// flight under the current compute phase. Live set ~58 VGPR (20 acc + 24
// double-buffer + addr/scratch) -> still inside the 64-VGPR / 8-waves-per-EU
// window, zero spill expected.
// History (previous session, 50-accumulator variants): launch_bounds caps and
// manual prefetch on the 50-acc layout all spilled; the dim-split 20-acc
// layout is what makes the rotation affordable.
__global__ void lanenet_accum(const float* __restrict__ emb,
                              const int* __restrict__ seg,
                              float* ws,
                              float* __restrict__ out) {
    const int b = blockIdx.y;
    const float* embB = emb + (size_t)b * DIM * NPIX;
    const int4* segB  = (const int4*)(seg + (size_t)b * NPIX);

    const int w    = threadIdx.x >> 6;   // wave id: dims 2w, 2w+1
    const int lane = threadIdx.x & 63;

    const float4* e0 = (const float4*)(embB + (size_t)(2 * w)     * NPIX);
    const float4* e1 = (const float4*)(embB + (size_t)(2 * w + 1) * NPIX);

    v2f cs[NCLS];   // (cnt, sq)
    v2f sm[NCLS];   // (sm0, sm1)
    #pragma unroll
    for (int c = 0; c < NCLS; ++c) {
        cs[c] = (v2f){0.0f, 0.0f};
        sm[c] = (v2f){0.0f, 0.0f};
    }

    auto pix = [&](int s, float av, float bv) {
        const float n2 = fmaf(av, av, bv * bv);   // partial |x|^2 (2 dims)
        const v2f ab = (v2f){av, bv};
        const v2f w1 = (v2f){1.0f, n2};
        #pragma unroll
        for (int c = 0; c < NCLS; ++c) {
            const float sel = (s == c) ? 1.0f : 0.0f;
            const v2f sv = (v2f){sel, sel};
            cs[c] = __builtin_elementwise_fma(sv, w1, cs[c]);  // cnt+=sel; sq=fma(sel,n2,sq)
            sm[c] = __builtin_elementwise_fma(sv, ab, sm[c]);  // sm0/sm1 fma
        }
    };

    int g = blockIdx.x * 64 + lane;
    int4   s4 = segB[g];
    float4 xa = e0[g];
    float4 xb = e1[g];

    #pragma unroll 1
    for (int it = 0; it < NIT - 1; ++it) {
        const int gn = g + PBLK * 64;
        const int4   s4n = segB[gn];   // next-iter loads issued before compute
        const float4 xan = e0[gn];
        const float4 xbn = e1[gn];

        pix(s4.x, xa.x, xb.x);
        pix(s4.y, xa.y, xb.y);
        pix(s4.z, xa.z, xb.z);
        pix(s4.w, xa.w, xb.w);

        s4 = s4n; xa = xan; xb = xbn; g = gn;
    }
    pix(s4.x, xa.x, xb.x);
    pix(s4.y, xa.y, xb.y);
    pix(s4.z, xa.z, xb.z);
    pix(s4.w, xa.w, xb.w);

    // wave shuffle-reduce -> LDS -> 50 atomics per block (identical ordering
    // to the verified version: absmax was 0.0)
    __shared__ float r_cnt[NCLS];
    __shared__ float r_sq[NWAVE][NCLS];
    __shared__ float r_sm[NCLS][DIM];

    #pragma unroll
    for (int c = 0; c < NCLS; ++c) {
        float v = wave_sum(cs[c].y);
        if (lane == 0) r_sq[w][c] = v;
        v = wave_sum(sm[c].x);
        if (lane == 0) r_sm[c][2 * w] = v;
        v = wave_sum(sm[c].y);
        if (lane == 0) r_sm[c][2 * w + 1] = v;
        v = wave_sum(cs[c].x);
        if (lane == 0 && w == 0) r_cnt[c] = v;
    }
    __syncthreads();

    if (threadIdx.x < ACC50) {
        const int c = threadIdx.x / 10;
        const int k = threadIdx.x % 10;
        float v;
        if (k == 0)      v = r_cnt[c];
        else if (k == 1) v = r_sq[0][c] + r_sq[1][c] + r_sq[2][c] + r_sq[3][c];
        else             v = r_sm[c][k - 2];
        atomicAdd(&ws[(size_t)b * ACC50 + threadIdx.x], v);
    }

    // ---- fused finalize: last block to finish does the tiny epilogue ----
    __threadfence();        // order this block's data atomics before ticket
    __syncthreads();
    __shared__ int amLast;
    if (threadIdx.x == 0) {
        unsigned* tick = (unsigned*)(ws + WS_FLOATS);
        amLast = (atomicAdd(tick, 1u) == (unsigned)(NBLOCKS - 1));
    }
    __syncthreads();
    if (!amLast) return;

    // device-scope coherent read-back of all 400 accumulators
    __shared__ float a[WS_FLOATS];
    for (int i = threadIdx.x; i < WS_FLOATS; i += TPB)
        a[i] = atomicAdd(&ws[i], 0.0f);
    __syncthreads();

    __shared__ float lsamp[BATCH];
    const int t = threadIdx.x;
    if (t < BATCH) {
        const float* ab = a + t * ACC50;
        float m[NCLS][DIM];
        float var = 0.0f;
        #pragma unroll
        for (int c = 0; c < NCLS; ++c) {
            const float c0 = fmaxf(ab[c * 10 + 0], 1.0f);
            const float qq = ab[c * 10 + 1];
            float s2 = 0.0f;
            #pragma unroll
            for (int d = 0; d < DIM; ++d) {
                const float s = ab[c * 10 + 2 + d];
                m[c][d] = s / c0;
                s2 = fmaf(s, s, s2);
            }
            float ss = qq - s2 / c0;            // sum of squared residuals
            ss = fmaxf(ss, 0.0f);
            var += fmaxf(sqrtf(ss) - SIGMA_V, 0.0f);
        }
        var *= (1.0f / NCLS);

        float dist = 0.0f;
        #pragma unroll
        for (int i = 0; i < NCLS; ++i) {
            #pragma unroll
            for (int j = i + 1; j < NCLS; ++j) {
                float d2 = 0.0f;
                #pragma unroll
                for (int d = 0; d < DIM; ++d) {
                    const float df = m[i][d] - m[j][d];
                    d2 = fmaf(df, df, d2);
                }
                dist += 2.0f * fmaxf(SIGMA_D - sqrtf(d2), 0.0f);
            }
        }
        dist *= (1.0f / (NCLS * (NCLS - 1)));

        lsamp[t] = var + dist;
    }
    __syncthreads();
    if (t == 0) {
        float s = 0.0f;
        #pragma unroll
        for (int bb = 0; bb < BATCH; ++bb) s += lsamp[bb];
        out[0] = s * (1.0f / BATCH);
    }
}

extern "C" void kernel_launch(void* const* d_in, const int* in_sizes, int n_in,
                              void* d_out, int out_size, void* d_ws, size_t ws_size,
                              hipStream_t stream) {
    (void)in_sizes; (void)n_in; (void)out_size; (void)ws_size;
    const float* emb = (const float*)d_in[0];
    const int*   seg = (const int*)d_in[1];
    float* out = (float*)d_out;
    float* ws  = (float*)d_ws;

    lanenet_init_ws<<<1, 512, 0, stream>>>(ws);
    dim3 grid(PBLK, BATCH);
    lanenet_accum<<<grid, TPB, 0, stream>>>(emb, seg, ws, out);
}

// Round 2
// 703.759 us; speedup vs baseline: 1.0043x; 1.0043x over previous
//
#include <hip/hip_runtime.h>

// Problem constants (fixed shapes from setup_inputs)
#define BATCH   8
#define DIM     8
#define NPIX    (1024 * 1024)
#define NCLS    5
#define SIGMA_V 0.5f
#define SIGMA_D 3.0f

#define PBLK 256   // blocks per sample (2048 total = 8 blocks/CU)
#define TPB  256   // threads per block = 4 waves
#define NWAVE (TPB / 64)
#define NBLOCKS (PBLK * BATCH)   // 2048

// ws layout: float ws[BATCH][NCLS][10] -> per (b,c): [count, sumsq, sum[0..7]]
// then one uint ticket counter at ws[WS_FLOATS]
#define ACC50 (NCLS * 10)
#define WS_FLOATS (BATCH * ACC50)   // 400
#define WS_TOTAL  (WS_FLOATS + 4)

__global__ void lanenet_init_ws(float* __restrict__ ws) {
    int t = blockIdx.x * blockDim.x + threadIdx.x;
    if (t < WS_TOTAL) ws[t] = 0.0f;   // zeroes accumulators AND ticket
}

__device__ __forceinline__ float wave_sum(float v) {
    #pragma unroll
    for (int off = 32; off > 0; off >>= 1)
        v += __shfl_xor(v, off, 64);
    return v;
}

// Dim-split accumulation: wave w handles dims {2w, 2w+1} over the SAME pixel
// range. Per-thread accumulators: cnt[5] + sq_partial[5] + sm[5][2] = 20
// (vs 50 when one thread handled all 8 dims). Live set ~46 VGPRs -> fits the
// allocator's preferred 64-VGPR/8-waves-per-EU target with ZERO spill.
// History of fighting the allocator instead:
//   R1 (50 acc, no bounds):            VGPR=64, spill, accum 440us
//   R2 (+launch_bounds(256,4)):        still spilled, accum ~160us
//   R3 (+manual prefetch unroll):      VGPR=64, 1.1GB scratch traffic, 561us
//   R4 (+waves_per_eu(4,4)):           accum still ~145us
//   Polish R1 (v2f pack + 1-deep rotation + unroll 1): VGPR=36 (!) -- the
//     allocator went remat-by-reload; kernel became L1-issue-bound, 458us,
//     duration independent of cache residency. DO NOT hand-pipeline this
//     loop; the compiler's schedule of the plain strided form is the fast one.
// sq is decomposed into per-dim-pair partials (summed at reduction, exact).
// seg is read by all 4 waves (same addresses -> L1 broadcast).
__global__ void lanenet_accum(const float* __restrict__ emb,
                              const int* __restrict__ seg,
                              float* __restrict__ ws,
                              float* __restrict__ out) {
    const int b = blockIdx.y;
    const float* embB = emb + (size_t)b * DIM * NPIX;
    const int4* segB  = (const int4*)(seg + (size_t)b * NPIX);

    const int w    = threadIdx.x >> 6;   // wave id: dims 2w, 2w+1
    const int lane = threadIdx.x & 63;

    const float4* e0 = (const float4*)(embB + (size_t)(2 * w)     * NPIX);
    const float4* e1 = (const float4*)(embB + (size_t)(2 * w + 1) * NPIX);

    float cnt[NCLS], sq[NCLS], sm0[NCLS], sm1[NCLS];
    #pragma unroll
    for (int c = 0; c < NCLS; ++c) {
        cnt[c] = 0.0f; sq[c] = 0.0f; sm0[c] = 0.0f; sm1[c] = 0.0f;
    }

    const int nG = NPIX / 4;             // float4 groups per sample (262144)
    const int stride = PBLK * 64;        // all waves cover the same g range

    for (int g = blockIdx.x * 64 + lane; g < nG; g += stride) {
        const int4 s4 = segB[g];
        const float4 xa = e0[g];
        const float4 xb = e1[g];

        #pragma unroll
        for (int p = 0; p < 4; ++p) {
            const int s =
                (p == 0) ? s4.x : (p == 1) ? s4.y : (p == 2) ? s4.z : s4.w;
            const float av =
                (p == 0) ? xa.x : (p == 1) ? xa.y : (p == 2) ? xa.z : xa.w;
            const float bv =
                (p == 0) ? xb.x : (p == 1) ? xb.y : (p == 2) ? xb.z : xb.w;

            const float n2 = fmaf(av, av, bv * bv);  // partial |x|^2 (2 dims)

            #pragma unroll
            for (int c = 0; c < NCLS; ++c) {
                const float sel = (s == c) ? 1.0f : 0.0f;
                cnt[c] += sel;                       // all waves; wave0's used
                sq[c]  = fmaf(sel, n2, sq[c]);
                sm0[c] = fmaf(sel, av, sm0[c]);
                sm1[c] = fmaf(sel, bv, sm1[c]);
            }
        }
    }

    // wave shuffle-reduce -> LDS -> 50 atomics per block
    __shared__ float r_cnt[NCLS];
    __shared__ float r_sq[NWAVE][NCLS];
    __shared__ float r_sm[NCLS][DIM];

    #pragma unroll
    for (int c = 0; c < NCLS; ++c) {
        float v = wave_sum(sq[c]);
        if (lane == 0) r_sq[w][c] = v;
        v = wave_sum(sm0[c]);
        if (lane == 0) r_sm[c][2 * w] = v;
        v = wave_sum(sm1[c]);
        if (lane == 0) r_sm[c][2 * w + 1] = v;
        v = wave_sum(cnt[c]);
        if (lane == 0 && w == 0) r_cnt[c] = v;
    }
    __syncthreads();

    if (threadIdx.x < ACC50) {
        const int c = threadIdx.x / 10;
        const int k = threadIdx.x % 10;
        float v;
        if (k == 0)      v = r_cnt[c];
        else if (k == 1) v = r_sq[0][c] + r_sq[1][c] + r_sq[2][c] + r_sq[3][c];
        else             v = r_sm[c][k - 2];
        atomicAdd(&ws[(size_t)b * ACC50 + threadIdx.x], v);
    }

    // ---- fused finalize: last block to increment the ticket runs the tiny
    // epilogue (saves the dependent 1-block launch behind a full-device
    // drain). Epilogue live ranges don't overlap the loop's, so it cannot
    // raise loop VGPR pressure. ----
    __threadfence();        // release: order data atomics before ticket
    __syncthreads();
    __shared__ int amLast;
    if (threadIdx.x == 0) {
        unsigned* tick = (unsigned*)(ws + WS_FLOATS);
        amLast = (atomicAdd(tick, 1u) == (unsigned)(NBLOCKS - 1));
    }
    __syncthreads();
    if (!amLast) return;
    __threadfence();        // acquire side

    // device-scope coherent read-back of all 400 accumulators
    __shared__ float a[WS_FLOATS];
    for (int i = threadIdx.x; i < WS_FLOATS; i += TPB)
        a[i] = atomicAdd(&ws[i], 0.0f);
    __syncthreads();

    __shared__ float lsamp[BATCH];
    const int t = threadIdx.x;
    if (t < BATCH) {
        const float* ab = a + t * ACC50;
        float m[NCLS][DIM];
        float var = 0.0f;
        #pragma unroll
        for (int c = 0; c < NCLS; ++c) {
            const float c0 = fmaxf(ab[c * 10 + 0], 1.0f);
            const float qq = ab[c * 10 + 1];
            float s2 = 0.0f;
            #pragma unroll
            for (int d = 0; d < DIM; ++d) {
                const float s = ab[c * 10 + 2 + d];
                m[c][d] = s / c0;
                s2 = fmaf(s, s, s2);
            }
            float ss = qq - s2 / c0;            // sum of squared residuals
            ss = fmaxf(ss, 0.0f);
            var += fmaxf(sqrtf(ss) - SIGMA_V, 0.0f);
        }
        var *= (1.0f / NCLS);

        float dist = 0.0f;
        #pragma unroll
        for (int i = 0; i < NCLS; ++i) {
            #pragma unroll
            for (int j = i + 1; j < NCLS; ++j) {
                float d2 = 0.0f;
                #pragma unroll
                for (int d = 0; d < DIM; ++d) {
                    const float df = m[i][d] - m[j][d];
                    d2 = fmaf(df, df, d2);
                }
                dist += 2.0f * fmaxf(SIGMA_D - sqrtf(d2), 0.0f);
            }
        }
        dist *= (1.0f / (NCLS * (NCLS - 1)));

        lsamp[t] = var + dist;
    }
    __syncthreads();
    if (t == 0) {
        float s = 0.0f;
        #pragma unroll
        for (int bb = 0; bb < BATCH; ++bb) s += lsamp[bb];
        out[0] = s * (1.0f / BATCH);
    }
}

extern "C" void kernel_launch(void* const* d_in, const int* in_sizes, int n_in,
                              void* d_out, int out_size, void* d_ws, size_t ws_size,
                              hipStream_t stream) {
    (void)in_sizes; (void)n_in; (void)out_size; (void)ws_size;
    const float* emb = (const float*)d_in[0];
    const int*   seg = (const int*)d_in[1];
    float* out = (float*)d_out;
    float* ws  = (float*)d_ws;

    lanenet_init_ws<<<1, 512, 0, stream>>>(ws);
    dim3 grid(PBLK, BATCH);
    lanenet_accum<<<grid, TPB, 0, stream>>>(emb, seg, ws, out);
}

// Round 3
// 386.654 us; speedup vs baseline: 1.8280x; 1.8201x over previous
//
#include <hip/hip_runtime.h>

// Problem constants (fixed shapes from setup_inputs)
#define BATCH   8
#define DIM     8
#define NPIX    (1024 * 1024)
#define NCLS    5
#define SIGMA_V 0.5f
#define SIGMA_D 3.0f

#define PBLK 256   // blocks per sample (2048 total = 8 blocks/CU)
#define TPB  256   // threads per block = 4 waves
#define NWAVE (TPB / 64)

// ws layout: float ws[BATCH][NCLS][10]  -> per (b,c): [count, sumsq, sum[0..7]]
#define ACC50 (NCLS * 10)
#define WS_FLOATS (BATCH * ACC50)

__global__ void lanenet_init_ws(float* __restrict__ ws) {
    int t = blockIdx.x * blockDim.x + threadIdx.x;
    if (t < WS_FLOATS) ws[t] = 0.0f;
}

__device__ __forceinline__ float wave_sum(float v) {
    #pragma unroll
    for (int off = 32; off > 0; off >>= 1)
        v += __shfl_xor(v, off, 64);
    return v;
}

// Dim-split accumulation: wave w handles dims {2w, 2w+1} over the SAME pixel
// range. Per-thread accumulators: cnt[5] + sq_partial[5] + sm[5][2] = 20
// (vs 50 when one thread handled all 8 dims). Live set ~46 VGPRs -> fits the
// allocator's preferred 64-VGPR/8-waves-per-EU target with ZERO spill.
// History of fighting the allocator instead:
//   R1 (50 acc, no bounds):            VGPR=64, spill, accum 440us
//   R2 (+launch_bounds(256,4)):        still spilled, accum ~160us
//   R3 (+manual prefetch unroll):      VGPR=64, 1.1GB scratch traffic, 561us
//   R4 (+waves_per_eu(4,4)):           accum still ~145us
// Polish-session history (DO NOT retry):
//   P1 (v2f pack + 1-deep load rotation): VGPR=36, remat-by-reload codegen,
//      458us, duration independent of cache residency.
//   P2 (verbatim loop + fused last-block finalize): VGPR=32 (!), 450us, same
//      symptom. The mere PRESENCE of the epilogue in the same function flips
//      the allocator into minimum-pressure mode and wrecks the loop schedule.
//      Fusing finalize can save at most ~5us of launch/drain; not worth it.
// sq is decomposed into per-dim-pair partials (summed at reduction, exact).
// seg is read by all 4 waves (same addresses -> L1 broadcast).
__global__ void lanenet_accum(const float* __restrict__ emb,
                              const int* __restrict__ seg,
                              float* __restrict__ ws) {
    const int b = blockIdx.y;
    const float* embB = emb + (size_t)b * DIM * NPIX;
    const int4* segB  = (const int4*)(seg + (size_t)b * NPIX);

    const int w    = threadIdx.x >> 6;   // wave id: dims 2w, 2w+1
    const int lane = threadIdx.x & 63;

    const float4* e0 = (const float4*)(embB + (size_t)(2 * w)     * NPIX);
    const float4* e1 = (const float4*)(embB + (size_t)(2 * w + 1) * NPIX);

    float cnt[NCLS], sq[NCLS], sm0[NCLS], sm1[NCLS];
    #pragma unroll
    for (int c = 0; c < NCLS; ++c) {
        cnt[c] = 0.0f; sq[c] = 0.0f; sm0[c] = 0.0f; sm1[c] = 0.0f;
    }

    const int nG = NPIX / 4;             // float4 groups per sample (262144)
    const int stride = PBLK * 64;        // all waves cover the same g range

    for (int g = blockIdx.x * 64 + lane; g < nG; g += stride) {
        const int4 s4 = segB[g];
        const float4 xa = e0[g];
        const float4 xb = e1[g];

        #pragma unroll
        for (int p = 0; p < 4; ++p) {
            const int s =
                (p == 0) ? s4.x : (p == 1) ? s4.y : (p == 2) ? s4.z : s4.w;
            const float av =
                (p == 0) ? xa.x : (p == 1) ? xa.y : (p == 2) ? xa.z : xa.w;
            const float bv =
                (p == 0) ? xb.x : (p == 1) ? xb.y : (p == 2) ? xb.z : xb.w;

            const float n2 = fmaf(av, av, bv * bv);  // partial |x|^2 (2 dims)

            #pragma unroll
            for (int c = 0; c < NCLS; ++c) {
                const float sel = (s == c) ? 1.0f : 0.0f;
                cnt[c] += sel;                       // all waves; wave0's used
                sq[c]  = fmaf(sel, n2, sq[c]);
                sm0[c] = fmaf(sel, av, sm0[c]);
                sm1[c] = fmaf(sel, bv, sm1[c]);
            }
        }
    }

    // wave shuffle-reduce -> LDS -> 50 atomics per block
    __shared__ float r_cnt[NCLS];
    __shared__ float r_sq[NWAVE][NCLS];
    __shared__ float r_sm[NCLS][DIM];

    #pragma unroll
    for (int c = 0; c < NCLS; ++c) {
        float v = wave_sum(sq[c]);
        if (lane == 0) r_sq[w][c] = v;
        v = wave_sum(sm0[c]);
        if (lane == 0) r_sm[c][2 * w] = v;
        v = wave_sum(sm1[c]);
        if (lane == 0) r_sm[c][2 * w + 1] = v;
        v = wave_sum(cnt[c]);
        if (lane == 0 && w == 0) r_cnt[c] = v;
    }
    __syncthreads();

    if (threadIdx.x < ACC50) {
        const int c = threadIdx.x / 10;
        const int k = threadIdx.x % 10;
        float v;
        if (k == 0)      v = r_cnt[c];
        else if (k == 1) v = r_sq[0][c] + r_sq[1][c] + r_sq[2][c] + r_sq[3][c];
        else             v = r_sm[c][k - 2];
        atomicAdd(&ws[(size_t)b * ACC50 + threadIdx.x], v);
    }
}

__global__ void lanenet_finalize(const float* __restrict__ ws,
                                 float* __restrict__ out) {
    __shared__ float lsamp[BATCH];
    const int t = threadIdx.x;
    if (t < BATCH) {
        const float* a = ws + (size_t)t * ACC50;
        float m[NCLS][DIM];
        float var = 0.0f;
        #pragma unroll
        for (int c = 0; c < NCLS; ++c) {
            const float c0 = fmaxf(a[c * 10 + 0], 1.0f);
            const float qq = a[c * 10 + 1];
            float s2 = 0.0f;
            #pragma unroll
            for (int d = 0; d < DIM; ++d) {
                const float s = a[c * 10 + 2 + d];
                m[c][d] = s / c0;
                s2 = fmaf(s, s, s2);
            }
            float ss = qq - s2 / c0;            // sum of squared residuals
            ss = fmaxf(ss, 0.0f);
            var += fmaxf(sqrtf(ss) - SIGMA_V, 0.0f);
        }
        var *= (1.0f / NCLS);

        float dist = 0.0f;
        #pragma unroll
        for (int i = 0; i < NCLS; ++i) {
            #pragma unroll
            for (int j = i + 1; j < NCLS; ++j) {
                float d2 = 0.0f;
                #pragma unroll
                for (int d = 0; d < DIM; ++d) {
                    const float df = m[i][d] - m[j][d];
                    d2 = fmaf(df, df, d2);
                }
                dist += 2.0f * fmaxf(SIGMA_D - sqrtf(d2), 0.0f);
            }
        }
        dist *= (1.0f / (NCLS * (NCLS - 1)));

        lsamp[t] = var + dist;
    }
    __syncthreads();
    if (t == 0) {
        float s = 0.0f;
        #pragma unroll
        for (int b = 0; b < BATCH; ++b) s += lsamp[b];
        out[0] = s * (1.0f / BATCH);
    }
}

extern "C" void kernel_launch(void* const* d_in, const int* in_sizes, int n_in,
                              void* d_out, int out_size, void* d_ws, size_t ws_size,
                              hipStream_t stream) {
    (void)in_sizes; (void)n_in; (void)out_size; (void)ws_size;
    const float* emb = (const float*)d_in[0];
    const int*   seg = (const int*)d_in[1];
    float* out = (float*)d_out;
    float* ws  = (float*)d_ws;

    lanenet_init_ws<<<1, 512, 0, stream>>>(ws);
    dim3 grid(PBLK, BATCH);
    lanenet_accum<<<grid, TPB, 0, stream>>>(emb, seg, ws);
    lanenet_finalize<<<1, 64, 0, stream>>>(ws, out);
}